// Round 9
// baseline (341.062 us; speedup 1.0000x reference)
//
#include <hip/hip_runtime.h>
#include <cstdint>
#include <cstring>

namespace {
constexpr uint32_t kTableSize = 524288u;   // 2^19
constexpr uint32_t kTableMask = kTableSize - 1u;
constexpr uint32_t kP1 = 2654435761u;
constexpr uint32_t kP2 = 805459861u;
constexpr int kLutTotal = 1075325;         // sum of D^3, D = res+1, levels 0..7
}

typedef double v2d __attribute__((ext_vector_type(2)));

// floor(16 * (2^(1/3))^l) for l=0..15 (validated: rounds 1-8 passed)
__constant__ float c_res[16] = {16.f, 20.f, 25.f, 32.f, 40.f, 50.f, 64.f, 80.f,
                                101.f, 128.f, 161.f, 203.f, 256.f, 322.f, 406.f, 512.f};
// dense-LUT geometry for coarse levels 0..7: D = res+1, offsets = cumsum(D^3)
__constant__ uint32_t c_dim[8]     = {17, 21, 26, 33, 41, 51, 65, 81};
__constant__ uint32_t c_lut_off[8] = {0, 4913, 14174, 31750, 67687, 136608, 269259, 543884};

// ---------------- hashed trilinear interp (fine levels + fallback) ---------
__device__ __forceinline__ double hash_interp(const float2* __restrict__ tbl,
                                              float px, float py, float pz,
                                              float res)
{
    const float nx = fminf(fmaxf((px + 1.0f) * 0.5f, 0.0f), 0.999999f);
    const float ny = fminf(fmaxf((py + 1.0f) * 0.5f, 0.0f), 0.999999f);
    const float nz = fminf(fmaxf((pz + 1.0f) * 0.5f, 0.0f), 0.999999f);

    const float sx = nx * res, sy = ny * res, sz = nz * res;
    const float fx = floorf(sx), fy = floorf(sy), fz = floorf(sz);
    const float wx = sx - fx, wy = sy - fy, wz = sz - fz;
    const float ixw = 1.0f - wx, iyw = 1.0f - wy, izw = 1.0f - wz;

    const uint32_t cx = (uint32_t)fx;
    const uint32_t cy = (uint32_t)fy;
    const uint32_t cz = (uint32_t)fz;

    const uint32_t hy0 = cy * kP1;    const uint32_t hy1 = hy0 + kP1;
    const uint32_t hz0 = cz * kP2;    const uint32_t hz1 = hz0 + kP2;

    const uint32_t b00 = cx ^ hy0 ^ hz0;
    const uint32_t b10 = cx ^ hy1 ^ hz0;
    const uint32_t b01 = cx ^ hy0 ^ hz1;
    const uint32_t b11 = cx ^ hy1 ^ hz1;

    float2 g0, g1, g2, g3, g4, g5, g6, g7;

    if ((cx & 1u) == 0u) {
        // x-neighbor = idx^1 -> one aligned float4 per (y,z) combo
        const float* tf = reinterpret_cast<const float*>(tbl);
        {
            const uint32_t ia = b00 & kTableMask;
            const float4 q = *reinterpret_cast<const float4*>(tf + (ia & ~1u) * 2u);
            const bool hi = (ia & 1u);
            g0 = hi ? make_float2(q.z, q.w) : make_float2(q.x, q.y);
            g1 = hi ? make_float2(q.x, q.y) : make_float2(q.z, q.w);
        }
        {
            const uint32_t ia = b10 & kTableMask;
            const float4 q = *reinterpret_cast<const float4*>(tf + (ia & ~1u) * 2u);
            const bool hi = (ia & 1u);
            g2 = hi ? make_float2(q.z, q.w) : make_float2(q.x, q.y);
            g4 = hi ? make_float2(q.x, q.y) : make_float2(q.z, q.w);
        }
        {
            const uint32_t ia = b01 & kTableMask;
            const float4 q = *reinterpret_cast<const float4*>(tf + (ia & ~1u) * 2u);
            const bool hi = (ia & 1u);
            g3 = hi ? make_float2(q.z, q.w) : make_float2(q.x, q.y);
            g5 = hi ? make_float2(q.x, q.y) : make_float2(q.z, q.w);
        }
        {
            const uint32_t ia = b11 & kTableMask;
            const float4 q = *reinterpret_cast<const float4*>(tf + (ia & ~1u) * 2u);
            const bool hi = (ia & 1u);
            g6 = hi ? make_float2(q.z, q.w) : make_float2(q.x, q.y);
            g7 = hi ? make_float2(q.x, q.y) : make_float2(q.z, q.w);
        }
    } else {
        const uint32_t cx1 = cx + 1u;
        g0 = tbl[(b00) & kTableMask];
        g1 = tbl[(cx1 ^ hy0 ^ hz0) & kTableMask];
        g2 = tbl[(b10) & kTableMask];
        g4 = tbl[(cx1 ^ hy1 ^ hz0) & kTableMask];
        g3 = tbl[(b01) & kTableMask];
        g5 = tbl[(cx1 ^ hy0 ^ hz1) & kTableMask];
        g6 = tbl[(b11) & kTableMask];
        g7 = tbl[(cx1 ^ hy1 ^ hz1) & kTableMask];
    }

    const float w0 = (ixw * iyw) * izw;
    const float w1 = (wx  * iyw) * izw;
    const float w2 = (ixw * wy ) * izw;
    const float w3 = (ixw * iyw) * wz;
    const float w4 = (wx  * wy ) * izw;
    const float w5 = (wx  * iyw) * wz;
    const float w6 = (ixw * wy ) * wz;
    const float w7 = (wx  * wy ) * wz;

    float a0 = w0 * g0.x;           float a1 = w0 * g0.y;
    a0 = fmaf(w1, g1.x, a0);        a1 = fmaf(w1, g1.y, a1);
    a0 = fmaf(w2, g2.x, a0);        a1 = fmaf(w2, g2.y, a1);
    a0 = fmaf(w3, g3.x, a0);        a1 = fmaf(w3, g3.y, a1);
    a0 = fmaf(w4, g4.x, a0);        a1 = fmaf(w4, g4.y, a1);
    a0 = fmaf(w5, g5.x, a0);        a1 = fmaf(w5, g5.y, a1);
    a0 = fmaf(w6, g6.x, a0);        a1 = fmaf(w6, g6.y, a1);
    a0 = fmaf(w7, g7.x, a0);        a1 = fmaf(w7, g7.y, a1);

    float2 r = make_float2(a0, a1);
    double rd;
    memcpy(&rd, &r, sizeof(rd));
    return rd;
}

__device__ __forceinline__ void load_xyz(const float* __restrict__ x, uint32_t p,
                                         float& px, float& py, float& pz)
{
    px = __builtin_nontemporal_load(x + p * 3u + 0u);
    py = __builtin_nontemporal_load(x + p * 3u + 1u);
    pz = __builtin_nontemporal_load(x + p * 3u + 2u);
}

// ---------- K0: build dense LUTs for levels 0..7 (into out-buffer scratch) -
// lut[off_l + x + D*(y + D*z)] = tbl_l[hash(x,y,z) & mask]  — same values,
// but memory-adjacent along x and with line-footprint == dense size.
__global__ __launch_bounds__(256) void lut_build_kernel(
    const float* __restrict__ tables,
    float2* __restrict__ lut,
    int total)
{
    const uint32_t g = blockIdx.x * 256u + threadIdx.x;
    if (g >= (uint32_t)total) return;

    uint32_t l = 0;
    #pragma unroll
    for (int i = 1; i < 8; ++i)
        if (g >= c_lut_off[i]) l = i;

    const uint32_t cell = g - c_lut_off[l];
    const uint32_t D = c_dim[l];
    const uint32_t z = cell / (D * D);
    const uint32_t rem = cell - z * D * D;
    const uint32_t y = rem / D;
    const uint32_t x = rem - y * D;

    const uint32_t h = (x ^ (y * kP1) ^ (z * kP2)) & kTableMask;
    const float2* __restrict__ tbl =
        reinterpret_cast<const float2*>(tables) + (size_t)l * kTableSize;
    lut[g] = tbl[h];
}

// ---------- K1: fine levels 8..15, one level per XCD (proven, 105 us) ------
__global__ __launch_bounds__(256) void fine_kernel(
    const float* __restrict__ x,
    const float* __restrict__ tables,
    double* __restrict__ wsrow,       // row for level 8; [l-8][N]
    int n_points)
{
    const uint32_t xcd = blockIdx.x & 7u;
    const uint32_t j   = blockIdx.x >> 3;
    const uint32_t l   = 8u + xcd;
    const uint32_t p   = j * 256u + threadIdx.x;
    if (p >= (uint32_t)n_points) return;

    float px, py, pz;
    load_xyz(x, p, px, py, pz);

    const float2* __restrict__ tbl =
        reinterpret_cast<const float2*>(tables) + (size_t)l * kTableSize;

    const double rd = hash_interp(tbl, px, py, pz, c_res[l]);
    __builtin_nontemporal_store(rd, wsrow + (size_t)xcd * (uint32_t)n_points + p);
}

// ---------- K2: coarse levels 0..7 via dense LUT, one level per XCD --------
// x-pair is ALWAYS adjacent in the dense LUT -> 4 (16 B) loads per point
// (vs avg 6 hashed). Line-footprints: l7 4.25 MB ... l0 39 KB (L1-hot).
__global__ __launch_bounds__(256) void coarse_dense_kernel(
    const float* __restrict__ x,
    const float2* __restrict__ lut,
    double* __restrict__ ws,          // [16][N] level-major, rows 0..7
    int n_points)
{
    const uint32_t l = blockIdx.x & 7u;   // == XCD (round-robin dispatch)
    const uint32_t j = blockIdx.x >> 3;
    const uint32_t p = j * 256u + threadIdx.x;
    if (p >= (uint32_t)n_points) return;

    float px, py, pz;
    load_xyz(x, p, px, py, pz);

    const float res = c_res[l];
    const uint32_t D = c_dim[l];
    const uint32_t off = c_lut_off[l];

    const float nx = fminf(fmaxf((px + 1.0f) * 0.5f, 0.0f), 0.999999f);
    const float ny = fminf(fmaxf((py + 1.0f) * 0.5f, 0.0f), 0.999999f);
    const float nz = fminf(fmaxf((pz + 1.0f) * 0.5f, 0.0f), 0.999999f);

    const float sx = nx * res, sy = ny * res, sz = nz * res;
    const float fx = floorf(sx), fy = floorf(sy), fz = floorf(sz);
    const float wx = sx - fx, wy = sy - fy, wz = sz - fz;
    const float ixw = 1.0f - wx, iyw = 1.0f - wy, izw = 1.0f - wz;

    const uint32_t cx = (uint32_t)fx;
    const uint32_t cy = (uint32_t)fy;
    const uint32_t cz = (uint32_t)fz;

    const uint32_t base = off + cx + D * (cy + D * cz);
    const float* lf = reinterpret_cast<const float*>(lut);

    // 4 x-pair loads (16 B each, 8 B aligned; straddles a line 1/16 of cases)
    float4 q00, q10, q01, q11;
    memcpy(&q00, lf + 2u * base,               16);   // (y0,z0): g0,g1
    memcpy(&q10, lf + 2u * (base + D),         16);   // (y1,z0): g2,g4
    memcpy(&q01, lf + 2u * (base + D * D),     16);   // (y0,z1): g3,g5
    memcpy(&q11, lf + 2u * (base + D + D * D), 16);   // (y1,z1): g6,g7

    const float w0 = (ixw * iyw) * izw;
    const float w1 = (wx  * iyw) * izw;
    const float w2 = (ixw * wy ) * izw;
    const float w3 = (ixw * iyw) * wz;
    const float w4 = (wx  * wy ) * izw;
    const float w5 = (wx  * iyw) * wz;
    const float w6 = (ixw * wy ) * wz;
    const float w7 = (wx  * wy ) * wz;

    float a0 = w0 * q00.x;          float a1 = w0 * q00.y;
    a0 = fmaf(w1, q00.z, a0);       a1 = fmaf(w1, q00.w, a1);
    a0 = fmaf(w2, q10.x, a0);       a1 = fmaf(w2, q10.y, a1);
    a0 = fmaf(w3, q01.x, a0);       a1 = fmaf(w3, q01.y, a1);
    a0 = fmaf(w4, q10.z, a0);       a1 = fmaf(w4, q10.w, a1);
    a0 = fmaf(w5, q01.z, a0);       a1 = fmaf(w5, q01.w, a1);
    a0 = fmaf(w6, q11.x, a0);       a1 = fmaf(w6, q11.y, a1);
    a0 = fmaf(w7, q11.z, a0);       a1 = fmaf(w7, q11.w, a1);

    float2 r = make_float2(a0, a1);
    double rd;
    memcpy(&rd, &r, sizeof(rd));
    __builtin_nontemporal_store(rd, ws + (size_t)l * (uint32_t)n_points + p);
}

// ---------- K3: full-row merge ws[16][N] -> out[N][16] (proven) ------------
__global__ __launch_bounds__(256) void merge_full_kernel(
    const double* __restrict__ ws,
    double* __restrict__ out,
    int n_points)
{
    __shared__ double tile[32][17];
    const uint32_t t  = threadIdx.x;
    const uint32_t p0 = blockIdx.x * 32u;

    #pragma unroll
    for (uint32_t r = 0; r < 2; ++r) {
        const uint32_t lvl = r * 8u + (t >> 5);
        const uint32_t pi  = t & 31u;
        const uint32_t p   = p0 + pi;
        double v = 0.0;
        if (p < (uint32_t)n_points)
            v = __builtin_nontemporal_load(ws + (size_t)lvl * (uint32_t)n_points + p);
        tile[pi][lvl] = v;
    }
    __syncthreads();
    {
        const uint32_t pi = t >> 3;
        const uint32_t j  = t & 7u;
        const uint32_t p  = p0 + pi;
        if (p < (uint32_t)n_points) {
            v2d v;
            v.x = tile[pi][2u * j + 0u];
            v.y = tile[pi][2u * j + 1u];
            __builtin_nontemporal_store(
                v, reinterpret_cast<v2d*>(out + (size_t)p * 16u) + j);
        }
    }
}

// ================= fallback paths (ws too small) ===========================
__global__ __launch_bounds__(256) void coarse_kernel_r4(
    const float* __restrict__ x,
    const float* __restrict__ tables,
    double* __restrict__ ws,
    int n_points, int n_half)
{
    const uint32_t s = blockIdx.x & 15u;
    const uint32_t j = blockIdx.x >> 4;
    const uint32_t l    = (s < 8u) ? s : (15u - s);
    const uint32_t base = (s < 8u) ? 0u : (uint32_t)n_half;
    const uint32_t lim  = (s < 8u) ? (uint32_t)n_half : (uint32_t)n_points;
    const uint32_t p = base + j * 256u + threadIdx.x;
    if (p >= lim) return;

    float px, py, pz;
    load_xyz(x, p, px, py, pz);

    const float2* __restrict__ tbl =
        reinterpret_cast<const float2*>(tables) + (size_t)l * kTableSize;

    const double rd = hash_interp(tbl, px, py, pz, c_res[l]);
    __builtin_nontemporal_store(rd, ws + (size_t)l * (uint32_t)n_points + p);
}

__global__ __launch_bounds__(256) void merge_half_kernel(
    const double* __restrict__ ws,
    double* __restrict__ out,
    int n_points, int slot_base)
{
    __shared__ double tile[32][9];
    const uint32_t t  = threadIdx.x;
    const uint32_t p0 = blockIdx.x * 32u;
    {
        const uint32_t lvl = t >> 5;
        const uint32_t pi  = t & 31u;
        const uint32_t p   = p0 + pi;
        double v = 0.0;
        if (p < (uint32_t)n_points)
            v = __builtin_nontemporal_load(ws + (size_t)lvl * (uint32_t)n_points + p);
        tile[pi][lvl] = v;
    }
    __syncthreads();
    {
        const uint32_t lvl = t & 7u;
        const uint32_t pi  = t >> 3;
        const uint32_t p   = p0 + pi;
        if (p < (uint32_t)n_points)
            __builtin_nontemporal_store(tile[pi][lvl],
                                        out + (size_t)p * 16u + (uint32_t)slot_base + lvl);
    }
}

__global__ __launch_bounds__(256) void hashenc_fallback(
    const float* __restrict__ x,
    const float* __restrict__ tables,
    float* __restrict__ out,
    int n_points)
{
    const uint32_t tid = blockIdx.x * 256u + threadIdx.x;
    const uint32_t p = tid >> 4;
    const uint32_t l = tid & 15u;
    if (p >= (uint32_t)n_points) return;

    const float px = x[p * 3u + 0u];
    const float py = x[p * 3u + 1u];
    const float pz = x[p * 3u + 2u];

    const float2* __restrict__ tbl =
        reinterpret_cast<const float2*>(tables) + (size_t)l * kTableSize;
    const double rd = hash_interp(tbl, px, py, pz, c_res[l]);
    __builtin_nontemporal_store(rd, reinterpret_cast<double*>(out) + (size_t)p * 16u + l);
}

extern "C" void kernel_launch(void* const* d_in, const int* in_sizes, int n_in,
                              void* d_out, int out_size, void* d_ws, size_t ws_size,
                              hipStream_t stream) {
    const float* x      = (const float*)d_in[0];   // [N,3] f32
    const float* tables = (const float*)d_in[1];   // [16, 524288, 2] f32
    float* out          = (float*)d_out;           // [N, 32] f32

    const int n_points = in_sizes[0] / 3;
    const size_t ws16 = (size_t)16 * (size_t)n_points * sizeof(double);
    const size_t ws8  = (size_t)8  * (size_t)n_points * sizeof(double);

    double* ws = (double*)d_ws;

    if (ws_size >= ws16 && (size_t)out_size * sizeof(float) >= (size_t)kLutTotal * 8u) {
        const int chunks_n = (n_points + 255) / 256;

        // K0: dense LUTs for levels 0..7 -> scratch in out (merge overwrites)
        float2* lut = reinterpret_cast<float2*>(out);
        lut_build_kernel<<<(kLutTotal + 255) / 256, 256, 0, stream>>>(
            tables, lut, kLutTotal);

        // K1: fine levels 8..15 -> ws rows 8..15 (one 4 MiB table per XCD L2)
        fine_kernel<<<chunks_n * 8, 256, 0, stream>>>(
            x, tables, ws + (size_t)8 * (uint32_t)n_points, n_points);

        // K2: coarse levels 0..7 via dense LUTs -> ws rows 0..7
        coarse_dense_kernel<<<chunks_n * 8, 256, 0, stream>>>(
            x, lut, ws, n_points);

        // K3: one merge, full 128 B output rows (overwrites LUT scratch)
        merge_full_kernel<<<(n_points + 31) / 32, 256, 0, stream>>>(
            ws, (double*)out, n_points);
    } else if (ws_size >= ws8) {
        // round-4 proven path (305 us)
        const int n_half = (n_points + 1) / 2;
        const int merge_grid = (n_points + 31) / 32;
        {
            const int chunks = (n_points + 255) / 256;
            fine_kernel<<<chunks * 8, 256, 0, stream>>>(x, tables, ws, n_points);
        }
        merge_half_kernel<<<merge_grid, 256, 0, stream>>>(ws, (double*)out, n_points, 8);
        {
            const int chunks = (n_half + 255) / 256;
            coarse_kernel_r4<<<chunks * 16, 256, 0, stream>>>(x, tables, ws, n_points, n_half);
        }
        merge_half_kernel<<<merge_grid, 256, 0, stream>>>(ws, (double*)out, n_points, 0);
    } else {
        const int total = n_points * 16;
        const int grid = (total + 255) / 256;
        hashenc_fallback<<<grid, 256, 0, stream>>>(x, tables, out, n_points);
    }
}